// Round 19
// baseline (271.835 us; speedup 1.0000x reference)
//
#include <hip/hip_runtime.h>
#include <math.h>

#define F_IN 3
#define CH 32
#define HEADS 4
#define C1_OUT 64
#define C2_OUT 128
#define LIN 256
#define NCLS 25
#define NBIN 8

typedef __attribute__((ext_vector_type(8))) short bf16x8;
typedef __attribute__((ext_vector_type(4))) float f32x4;

__device__ __forceinline__ float elu_f(float x) {
    return x > 0.f ? x : (__expf(x) - 1.f);
}

__device__ __forceinline__ unsigned short f2bf(float f) {
    union { float f; unsigned int u; } v; v.f = f;
    unsigned int u = v.u + 0x7fffu + ((v.u >> 16) & 1u);
    return (unsigned short)(u >> 16);
}

__device__ __forceinline__ float bf2f(unsigned short u) {
    union { unsigned int u; float f; } v; v.u = ((unsigned int)u) << 16;
    return v.f;
}

__device__ __forceinline__ void unpackq(unsigned lo, unsigned hi, float& x, float& y,
                                        float& z, float& w) {
    x = bf2f((unsigned short)(lo & 0xffffu));
    y = bf2f((unsigned short)(lo >> 16));
    z = bf2f((unsigned short)(hi & 0xffffu));
    w = bf2f((unsigned short)(hi >> 16));
}

__device__ __forceinline__ void softmax4(const float* __restrict__ c,
                                         float& q0, float& q1, float& q2, float& q3) {
    float c0 = c[0], c1 = c[1], c2 = c[2], c3 = c[3];
    float mx = fmaxf(fmaxf(c0, c1), fmaxf(c2, c3));
    float e0 = __expf(c0 - mx), e1 = __expf(c1 - mx);
    float e2 = __expf(c2 - mx), e3 = __expf(c3 - mx);
    float inv = 1.f / (e0 + e1 + e2 + e3);
    q0 = e0 * inv; q1 = e1 * inv; q2 = e2 * inv; q3 = e3 * inv;
}

__device__ __forceinline__ void qslot(const float4* __restrict__ pp, float4 pd,
                                      float c0, float c1, float c2, float c3,
                                      int sx, bool valid,
                                      unsigned& qlo, unsigned& qhi) {
    float4 ps = pp[sx];
    float t0 = ps.x - pd.x + c0;
    float t1 = ps.y - pd.y + c1;
    float t2 = ps.z - pd.z + c2;
    float t3 = ps.w - pd.w + c3;
    float mx = fmaxf(fmaxf(t0, t1), fmaxf(t2, t3));
    float s0 = __expf(t0 - mx), s1 = __expf(t1 - mx);
    float s2 = __expf(t2 - mx), s3 = __expf(t3 - mx);
    float inv = 1.f / (s0 + s1 + s2 + s3);
    qlo = qhi = 0u;
    if (valid) {
        qlo = (unsigned)f2bf(s0 * inv) | ((unsigned)f2bf(s1 * inv) << 16);
        qhi = (unsigned)f2bf(s2 * inv) | ((unsigned)f2bf(s3 * inv) << 16);
    }
}

// ---------------- fc0 + proj1: wave per 2 nodes ----------------------------
__global__ __launch_bounds__(256) void k_fc0(
    const float* __restrict__ x, const float* __restrict__ w,
    const float* __restrict__ b, const float* __restrict__ u,
    unsigned short* __restrict__ h0, float* __restrict__ p, int n_nodes) {
    int wid = (blockIdx.x * blockDim.x + threadIdx.x) >> 6;
    int lane = threadIdx.x & 63;
    int half = lane >> 5, c = lane & 31;
    int node = wid * 2 + half;
    if (node >= n_nodes) return;
    float acc = b[c];
#pragma unroll
    for (int i = 0; i < F_IN; ++i) acc += x[node * F_IN + i] * w[i * CH + c];
    unsigned short hb = f2bf(elu_f(acc));
    h0[(size_t)node * CH + c] = hb;
    float hv = bf2f(hb);
    float a0 = hv * u[c * HEADS + 0];
    float a1 = hv * u[c * HEADS + 1];
    float a2 = hv * u[c * HEADS + 2];
    float a3 = hv * u[c * HEADS + 3];
#pragma unroll
    for (int m = 16; m >= 1; m >>= 1) {
        a0 += __shfl_xor(a0, m, 32); a1 += __shfl_xor(a1, m, 32);
        a2 += __shfl_xor(a2, m, 32); a3 += __shfl_xor(a3, m, 32);
    }
    if (c == 0) {
        p[node * 4 + 0] = a0; p[node * 4 + 1] = a1;
        p[node * 4 + 2] = a2; p[node * 4 + 3] = a3;
    }
}

// ---------------- degree count, XCD-binned by dst --------------------------
__global__ void k_deg(const int* __restrict__ dst, int* __restrict__ deg,
                      int ne, int npb) {
    int bin = blockIdx.x & (NBIN - 1);
    int blk = blockIdx.x >> 3;
    int nblk = gridDim.x >> 3;
    int per = (ne + nblk - 1) / nblk;
    int start = blk * per;
    int end = start + per < ne ? start + per : ne;
    int lo = bin * npb, hi = lo + npb;
    for (int e = start + threadIdx.x; e < end; e += blockDim.x) {
        int d = dst[e];
        if (d >= lo && d < hi) atomicAdd(&deg[d], 1);
    }
}

// ---------------- fused two-level exclusive scan (last-block top scan) -----
#define SCAN_BS 1024
__global__ __launch_bounds__(SCAN_BS) void k_scan_a(
    const int* __restrict__ deg, int* __restrict__ offa,
    int* __restrict__ blksum, int* __restrict__ done, int n, int nblk) {
    __shared__ int buf[SCAN_BS];
    __shared__ int lastflag;
    int tid = threadIdx.x;
    int i = blockIdx.x * SCAN_BS + tid;
    int v = (i < n) ? deg[i] : 0;
    buf[tid] = v;
    __syncthreads();
    for (int s = 1; s < SCAN_BS; s <<= 1) {
        int t = (tid >= s) ? buf[tid - s] : 0;
        __syncthreads();
        buf[tid] += t;
        __syncthreads();
    }
    if (i < n) offa[i] = buf[tid] - v;
    if (tid == SCAN_BS - 1) atomicExch(&blksum[blockIdx.x], buf[tid]);
    __threadfence();
    __syncthreads();
    if (tid == 0) lastflag = (atomicAdd(done, 1) == nblk - 1) ? 1 : 0;
    __syncthreads();
    if (lastflag) {
        int vv = (tid < nblk) ? atomicAdd(&blksum[tid], 0) : 0;
        buf[tid] = vv;
        __syncthreads();
        for (int s = 1; s < SCAN_BS; s <<= 1) {
            int t = (tid >= s) ? buf[tid - s] : 0;
            __syncthreads();
            buf[tid] += t;
            __syncthreads();
        }
        if (tid < nblk) blksum[tid] = buf[tid] - vv;
        if (tid == nblk - 1) offa[n] = buf[tid];
    }
}

__global__ void k_scan_c(int* __restrict__ offa, int* __restrict__ cur,
                         const int* __restrict__ blksum, int n) {
    int i = blockIdx.x * blockDim.x + threadIdx.x;
    if (i < n) {
        int o = offa[i] + blksum[i >> 10];
        offa[i] = o;
        cur[i] = o;
    }
}

// ---------------- scatter src only, XCD-binned ------------------------------
__global__ void k_scatter(const int* __restrict__ eidx, int* __restrict__ cur,
                          int* __restrict__ ssrc, int ne, int npb) {
    int bin = blockIdx.x & (NBIN - 1);
    int blk = blockIdx.x >> 3;
    int nblk = gridDim.x >> 3;
    int per = (ne + nblk - 1) / nblk;
    int start = blk * per;
    int end = start + per < ne ? start + per : ne;
    int lo = bin * npb, hi = lo + npb;
    for (int e = start + threadIdx.x; e < end; e += blockDim.x) {
        int d = eidx[ne + e];
        if (d >= lo && d < hi) {
            int s = eidx[e];
            int pos = atomicAdd(&cur[d], 1);
            ssrc[pos] = s;
        }
    }
}

// ---------------- per-node head projection (conv2 only) --------------------
template<int IN>
__global__ void k_proj(const unsigned short* __restrict__ h,
                       const float* __restrict__ u,
                       float* __restrict__ p, int n_nodes) {
    int node = blockIdx.x * blockDim.x + threadIdx.x;
    if (node >= n_nodes) return;
    const unsigned short* hr = h + (size_t)node * IN;
    float a0 = 0.f, a1 = 0.f, a2 = 0.f, a3 = 0.f;
#pragma unroll
    for (int kb = 0; kb < IN; kb += 8) {
        uint4 uu = *(const uint4*)(hr + kb);
        unsigned int ws_[4] = {uu.x, uu.y, uu.z, uu.w};
#pragma unroll
        for (int j = 0; j < 4; ++j) {
            float vlo = bf2f((unsigned short)(ws_[j] & 0xffffu));
            float vhi = bf2f((unsigned short)(ws_[j] >> 16));
            int k0 = kb + j * 2, k1 = kb + j * 2 + 1;
            a0 = fmaf(vlo, u[k0 * HEADS + 0], a0); a0 = fmaf(vhi, u[k1 * HEADS + 0], a0);
            a1 = fmaf(vlo, u[k0 * HEADS + 1], a1); a1 = fmaf(vhi, u[k1 * HEADS + 1], a1);
            a2 = fmaf(vlo, u[k0 * HEADS + 2], a2); a2 = fmaf(vhi, u[k1 * HEADS + 2], a2);
            a3 = fmaf(vlo, u[k0 * HEADS + 3], a3); a3 = fmaf(vhi, u[k1 * HEADS + 3], a3);
        }
    }
    p[node * 4 + 0] = a0; p[node * 4 + 1] = a1;
    p[node * 4 + 2] = a2; p[node * 4 + 3] = a3;
}

// ---------------- merged weight prep + done-counter reset ------------------
__global__ void k_prepAll(const float* __restrict__ W1, unsigned short* __restrict__ B1,
                          const float* __restrict__ W2, unsigned short* __restrict__ B2,
                          const float* __restrict__ Wf, unsigned short* __restrict__ Bf,
                          const float* __restrict__ Wc, unsigned short* __restrict__ Bc,
                          int* __restrict__ done) {
    int idx = blockIdx.x * blockDim.x + threadIdx.x;
    if (idx == 0) *done = 0;
    if (idx < 8192) {                       // conv1: K=128 M=64 IN=32
        int o = idx / 128, j = idx % 128;
        int hh = j / 32, k = j % 32;
        B1[idx] = f2bf(W1[k * (HEADS * 64) + hh * 64 + o]);
    } else if (idx < 40960) {               // conv2: K=256 M=128 IN=64
        int i = idx - 8192;
        int o = i / 256, j = i % 256;
        int hh = j / 64, k = j % 64;
        B2[i] = f2bf(W2[k * (HEADS * 128) + hh * 128 + o]);
    } else if (idx < 73728) {               // fc1: K=128 M=256 transpose
        int i = idx - 40960;
        int o = i / 128, j = i % 128;
        Bf[i] = f2bf(Wf[j * 256 + o]);
    } else if (idx < 81920) {               // fc2: pad 25->32, K=256
        int i = idx - 73728;
        int o = i >> 8, k = i & 255;
        Bc[i] = f2bf(o < NCLS ? Wc[k * NCLS + o] : 0.f);
    }
}

// ============ fused conv1: agg (8 waves x 8 nodes -> LDS) + MFMA (K=128,M=64)
__global__ __launch_bounds__(512) void k_conv1(
    const unsigned short* __restrict__ h, const int* __restrict__ offa,
    const int* __restrict__ ssrc, const float* __restrict__ p,
    const float* __restrict__ cvec, const unsigned short* __restrict__ Bt,
    const float* __restrict__ bias, unsigned short* __restrict__ D, int n) {
    __shared__ unsigned short Al[64 * 128];   // 16 KB
    int tid = threadIdx.x;
    int w = tid >> 6, lane = tid & 63;
    int l16 = lane & 15, l4 = lane >> 4;
    int rowbase = blockIdx.x * 64;
    int half = lane >> 5, ch = lane & 31;
    int slot = lane & 7, sbase = lane & 56;
    const float4* pp = (const float4*)p;
    float c0 = cvec[0], c1 = cvec[1], c2 = cvec[2], c3 = cvec[3];
    float qc0, qc1, qc2, qc3;
    softmax4(cvec, qc0, qc1, qc2, qc3);

    // ---- agg phase: wave w handles nodes rowbase + w*8 .. +7 ----
    for (int i = 0; i < 8; ++i) {
        int lrow = w * 8 + i;
        int node = rowbase + lrow;
        if (node >= n) break;
        int e0 = __builtin_amdgcn_readfirstlane(offa[node]);
        int e1 = __builtin_amdgcn_readfirstlane(offa[node + 1]);
        float4 pd = pp[node];
        float a0 = 0.f, a1 = 0.f, a2 = 0.f, a3 = 0.f;
        for (int e = e0; e < e1; e += 8) {
            int ee = e + slot;
            int ec = ee < e1 ? ee : e0;
            int sx = ssrc[ec];
            unsigned qlo, qhi;
            qslot(pp, pd, c0, c1, c2, c3, sx, ee < e1, qlo, qhi);
#pragma unroll
            for (int m = 0; m < 4; ++m) {
                int src = sbase + 2 * m + half;
                int sj = __shfl(sx, src, 64);
                unsigned lo = (unsigned)__shfl((int)qlo, src, 64);
                unsigned hi = (unsigned)__shfl((int)qhi, src, 64);
                float xj = bf2f(h[(size_t)sj * CH + ch]);
                float qx, qy, qz, qw;
                unpackq(lo, hi, qx, qy, qz, qw);
                a0 = fmaf(qx, xj, a0); a1 = fmaf(qy, xj, a1);
                a2 = fmaf(qz, xj, a2); a3 = fmaf(qw, xj, a3);
            }
        }
        a0 += __shfl_xor(a0, 32); a1 += __shfl_xor(a1, 32);
        a2 += __shfl_xor(a2, 32); a3 += __shfl_xor(a3, 32);
        if (half == 0) {
            float xi = bf2f(h[(size_t)node * CH + ch]);
            a0 = fmaf(qc0, xi, a0); a1 = fmaf(qc1, xi, a1);
            a2 = fmaf(qc2, xi, a2); a3 = fmaf(qc3, xi, a3);
            float inv = 1.f / (float)(e1 - e0 + 1);
            float av[4] = {a0 * inv, a1 * inv, a2 * inv, a3 * inv};
#pragma unroll
            for (int q = 0; q < 4; ++q) {
                int colq = q * CH + ch;
                int byte = ((lrow * 128 + colq) * 2) ^ ((lrow & 7) << 4);
                *(unsigned short*)((char*)Al + byte) = f2bf(av[q]);
            }
        }
    }
    __syncthreads();

    // ---- mgemm phase: 8 waves: col group = w&3, row half = w>>2 ----
    bf16x8 bfr[4];
    int col = (w & 3) * 16 + l16;
#pragma unroll
    for (int t = 0; t < 4; ++t)
        bfr[t] = *(const bf16x8*)(Bt + (size_t)col * 128 + t * 32 + l4 * 8);
    float bv = bias[col];
    int rbase = (w >> 2) * 2;
#pragma unroll
    for (int rr = 0; rr < 2; ++rr) {
        int r = rbase + rr;
        bf16x8 af[4];
        int row = r * 16 + l16;
#pragma unroll
        for (int t = 0; t < 4; ++t) {
            int byte = ((row * 128 + t * 32 + l4 * 8) * 2) ^ ((row & 7) << 4);
            af[t] = *(bf16x8*)((char*)Al + byte);
        }
        f32x4 acc = {0.f, 0.f, 0.f, 0.f};
#pragma unroll
        for (int t = 0; t < 4; ++t)
            acc = __builtin_amdgcn_mfma_f32_16x16x32_bf16(af[t], bfr[t], acc, 0, 0, 0);
#pragma unroll
        for (int j = 0; j < 4; ++j) {
            int grow = rowbase + r * 16 + l4 * 4 + j;
            if (grow < n)
                D[(size_t)grow * 64 + col] = f2bf(elu_f(acc[j] + bv));
        }
    }
}

// ============ fused conv2: agg (8 waves x 8 nodes -> LDS) + MFMA (K=256,M=128)
__global__ __launch_bounds__(512) void k_conv2(
    const unsigned short* __restrict__ h, const int* __restrict__ offa,
    const int* __restrict__ ssrc, const float* __restrict__ p,
    const float* __restrict__ cvec, const unsigned short* __restrict__ Bt,
    const float* __restrict__ bias, unsigned short* __restrict__ D, int n) {
    __shared__ unsigned short Al[64 * 256];   // 32 KB
    int tid = threadIdx.x;
    int w = tid >> 6, lane = tid & 63;
    int l16 = lane & 15, l4 = lane >> 4;
    int rowbase = blockIdx.x * 64;
    int slot = lane & 7, sbase = lane & 56;
    const float4* pp = (const float4*)p;
    float c0 = cvec[0], c1 = cvec[1], c2 = cvec[2], c3 = cvec[3];
    float qc0, qc1, qc2, qc3;
    softmax4(cvec, qc0, qc1, qc2, qc3);

    // ---- agg phase ----
    for (int i = 0; i < 8; ++i) {
        int lrow = w * 8 + i;
        int node = rowbase + lrow;
        if (node >= n) break;
        int e0 = __builtin_amdgcn_readfirstlane(offa[node]);
        int e1 = __builtin_amdgcn_readfirstlane(offa[node + 1]);
        float4 pd = pp[node];
        float a0 = 0.f, a1 = 0.f, a2 = 0.f, a3 = 0.f;
        for (int e = e0; e < e1; e += 8) {
            int ee = e + slot;
            int ec = ee < e1 ? ee : e0;
            int sx = ssrc[ec];
            unsigned qlo, qhi;
            qslot(pp, pd, c0, c1, c2, c3, sx, ee < e1, qlo, qhi);
#pragma unroll
            for (int j = 0; j < 8; ++j) {
                int src = sbase + j;
                int sj = __shfl(sx, src, 64);
                unsigned lo = (unsigned)__shfl((int)qlo, src, 64);
                unsigned hi = (unsigned)__shfl((int)qhi, src, 64);
                float xj = bf2f(h[(size_t)sj * C1_OUT + lane]);
                float qx, qy, qz, qw;
                unpackq(lo, hi, qx, qy, qz, qw);
                a0 = fmaf(qx, xj, a0); a1 = fmaf(qy, xj, a1);
                a2 = fmaf(qz, xj, a2); a3 = fmaf(qw, xj, a3);
            }
        }
        float xi = bf2f(h[(size_t)node * C1_OUT + lane]);
        a0 = fmaf(qc0, xi, a0); a1 = fmaf(qc1, xi, a1);
        a2 = fmaf(qc2, xi, a2); a3 = fmaf(qc3, xi, a3);
        float inv = 1.f / (float)(e1 - e0 + 1);
        float av[4] = {a0 * inv, a1 * inv, a2 * inv, a3 * inv};
#pragma unroll
        for (int q = 0; q < 4; ++q) {
            int colq = q * C1_OUT + lane;
            int byte = ((lrow * 256 + colq) * 2) ^ ((lrow & 7) << 4);
            *(unsigned short*)((char*)Al + byte) = f2bf(av[q]);
        }
    }
    __syncthreads();

    // ---- mgemm phase: 8 waves x 16 cols, full r loop ----
    bf16x8 bfr[8];
    int col = w * 16 + l16;
#pragma unroll
    for (int t = 0; t < 8; ++t)
        bfr[t] = *(const bf16x8*)(Bt + (size_t)col * 256 + t * 32 + l4 * 8);
    float bv = bias[col];
#pragma unroll
    for (int r = 0; r < 4; ++r) {
        bf16x8 af[8];
        int row = r * 16 + l16;
#pragma unroll
        for (int t = 0; t < 8; ++t) {
            int byte = ((row * 256 + t * 32 + l4 * 8) * 2) ^ ((row & 7) << 4);
            af[t] = *(bf16x8*)((char*)Al + byte);
        }
        f32x4 acc = {0.f, 0.f, 0.f, 0.f};
#pragma unroll
        for (int t = 0; t < 8; ++t)
            acc = __builtin_amdgcn_mfma_f32_16x16x32_bf16(af[t], bfr[t], acc, 0, 0, 0);
#pragma unroll
        for (int j = 0; j < 4; ++j) {
            int grow = rowbase + r * 16 + l4 * 4 + j;
            if (grow < n)
                D[(size_t)grow * 128 + col] = f2bf(elu_f(acc[j] + bv));
        }
    }
}

// ---------------- fused head: fc1 in LDS -> fc2 + log_softmax --------------
__global__ __launch_bounds__(256) void k_head(
    const unsigned short* __restrict__ A, const unsigned short* __restrict__ Btf,
    const float* __restrict__ bias1, const unsigned short* __restrict__ Btc,
    const float* __restrict__ bias2, float* __restrict__ out, int n) {
    __shared__ unsigned short Al[64 * 128];   // 16 KB
    __shared__ unsigned short Hl[64 * 256];   // 32 KB
    int tid = threadIdx.x;
    int w = tid >> 6, l = tid & 63;
    int l16 = l & 15, l4 = l >> 4;
    int rowbase = blockIdx.x * 64;

    bf16x8 bfr[4][4];
#pragma unroll
    for (int c = 0; c < 4; ++c)
#pragma unroll
        for (int t = 0; t < 4; ++t) {
            int col = w * 64 + c * 16 + l16;
            int k = t * 32 + l4 * 8;
            bfr[c][t] = *(const bf16x8*)(Btf + (size_t)col * 128 + k);
        }

    for (int idx = tid; idx < 1024; idx += 256) {
        int row = idx >> 4;
        int kb = (idx & 15) * 8;
        int grow = rowbase + row;
        uint4 u;
        if (grow < n) u = *(const uint4*)(A + (size_t)grow * 128 + kb);
        else          u.x = u.y = u.z = u.w = 0u;
        int byte = ((row * 128 + kb) * 2) ^ ((row & 7) << 4);
        *(uint4*)((char*)Al + byte) = u;
    }
    __syncthreads();

#pragma unroll
    for (int r = 0; r < 4; ++r) {
        bf16x8 af[4];
        int row = r * 16 + l16;
#pragma unroll
        for (int t = 0; t < 4; ++t) {
            int byte = ((row * 128 + t * 32 + l4 * 8) * 2) ^ ((row & 7) << 4);
            af[t] = *(bf16x8*)((char*)Al + byte);
        }
#pragma unroll
        for (int c = 0; c < 4; ++c) {
            f32x4 acc = {0.f, 0.f, 0.f, 0.f};
#pragma unroll
            for (int t = 0; t < 4; ++t)
                acc = __builtin_amdgcn_mfma_f32_16x16x32_bf16(af[t], bfr[c][t], acc, 0, 0, 0);
            int col = w * 64 + c * 16 + l16;
            float bv = bias1[col];
#pragma unroll
            for (int j = 0; j < 4; ++j) {
                int lrow = r * 16 + l4 * 4 + j;
                unsigned short v = f2bf(elu_f(acc[j] + bv));
                int byte = ((lrow * 256 + col) * 2) ^ ((lrow & 7) << 4);
                *(unsigned short*)((char*)Hl + byte) = v;
            }
        }
    }
    __syncthreads();

    bf16x8 b0[8], b1[8];
#pragma unroll
    for (int t = 0; t < 8; ++t) {
        int k = t * 32 + l4 * 8;
        b0[t] = *(const bf16x8*)(Btc + (size_t)l16 * LIN + k);
        b1[t] = *(const bf16x8*)(Btc + (size_t)(16 + l16) * LIN + k);
    }
    float bb0 = bias2[l16];
    bool hi_ok = (l16 < NCLS - 16);
    float bb1 = hi_ok ? bias2[16 + l16] : 0.f;

    int lrow = w * 16 + l16;
    bf16x8 af[8];
#pragma unroll
    for (int t = 0; t < 8; ++t) {
        int byte = ((lrow * 256 + t * 32 + l4 * 8) * 2) ^ ((lrow & 7) << 4);
        af[t] = *(bf16x8*)((char*)Hl + byte);
    }
    f32x4 acc0 = {0.f, 0.f, 0.f, 0.f}, acc1 = {0.f, 0.f, 0.f, 0.f};
#pragma unroll
    for (int t = 0; t < 8; ++t) {
        acc0 = __builtin_amdgcn_mfma_f32_16x16x32_bf16(af[t], b0[t], acc0, 0, 0, 0);
        acc1 = __builtin_amdgcn_mfma_f32_16x16x32_bf16(af[t], b1[t], acc1, 0, 0, 0);
    }
#pragma unroll
    for (int j = 0; j < 4; ++j) {
        float v0 = acc0[j] + bb0;
        float v1 = acc1[j] + bb1;
        float m = fmaxf(v0, hi_ok ? v1 : -1e30f);
#pragma unroll
        for (int msk = 8; msk >= 1; msk >>= 1)
            m = fmaxf(m, __shfl_xor(m, msk, 16));
        float s = __expf(v0 - m) + (hi_ok ? __expf(v1 - m) : 0.f);
#pragma unroll
        for (int msk = 8; msk >= 1; msk >>= 1)
            s += __shfl_xor(s, msk, 16);
        float lse = m + __logf(s);
        int ro = rowbase + w * 16 + l4 * 4 + j;
        if (ro < n) {
            out[(size_t)ro * NCLS + l16] = v0 - lse;
            if (hi_ok) out[(size_t)ro * NCLS + 16 + l16] = v1 - lse;
        }
    }
}

extern "C" void kernel_launch(void* const* d_in, const int* in_sizes, int n_in,
                              void* d_out, int out_size, void* d_ws, size_t ws_size,
                              hipStream_t stream) {
    const float* x     = (const float*)d_in[0];
    const int*   eidx  = (const int*)d_in[1];
    const float* fc0_w = (const float*)d_in[2];
    const float* fc0_b = (const float*)d_in[3];
    const float* c1w   = (const float*)d_in[4];
    const float* c1u   = (const float*)d_in[5];
    const float* c1c   = (const float*)d_in[6];
    const float* c1b   = (const float*)d_in[7];
    const float* c2w   = (const float*)d_in[8];
    const float* c2u   = (const float*)d_in[9];
    const float* c2c   = (const float*)d_in[10];
    const float* c2b   = (const float*)d_in[11];
    const float* fc1w  = (const float*)d_in[12];
    const float* fc1b  = (const float*)d_in[13];
    const float* fc2w  = (const float*)d_in[14];
    const float* fc2b  = (const float*)d_in[15];

    int n_nodes = in_sizes[0] / F_IN;   // 50000
    int ne      = in_sizes[1] / 2;      // 800000

    // ---- workspace layout (float units) — NO aliasing (h2 separate) ----
    auto align4 = [](size_t v) { return (v + 3) & ~(size_t)3; };
    float* ws = (float*)d_ws;
    size_t t = 0;
    size_t off_o = t; t += align4((size_t)n_nodes + 1);
    size_t cur_o = t; t += align4((size_t)n_nodes);
    size_t blk_o = t; t += 64;
    size_t don_o = t; t += 4;
    size_t p_o   = t; t += align4((size_t)n_nodes * 4);
    size_t h1_o  = t; t += align4((size_t)n_nodes * 32);   // n*64 bf16
    size_t h2_o  = t; t += align4((size_t)n_nodes * 64);   // n*128 bf16 (own region!)
    size_t h0_o  = t; t += align4((size_t)n_nodes * 16);   // n*32 bf16
    size_t ss_o  = t; t += align4((size_t)ne);             // ssrc: int
    size_t bt1_o = t; t += 4096;
    size_t bt2_o = t; t += 16384;
    size_t btf_o = t; t += 16384;
    size_t btc_o = t; t += 4096;

    int*    offa   = (int*)(ws + off_o);
    int*    cur    = (int*)(ws + cur_o);
    int*    blksum = (int*)(ws + blk_o);
    int*    done   = (int*)(ws + don_o);
    float*  p      = ws + p_o;
    unsigned short* h1  = (unsigned short*)(ws + h1_o);
    unsigned short* h2  = (unsigned short*)(ws + h2_o);
    unsigned short* h0  = (unsigned short*)(ws + h0_o);
    int*    ssrc   = (int*)(ws + ss_o);
    unsigned short* bt1 = (unsigned short*)(ws + bt1_o);
    unsigned short* bt2 = (unsigned short*)(ws + bt2_o);
    unsigned short* btf = (unsigned short*)(ws + btf_o);
    unsigned short* btc = (unsigned short*)(ws + btc_o);
    float*  out    = (float*)d_out;

    int nblk = (n_nodes + SCAN_BS - 1) / SCAN_BS;
    int npb  = (n_nodes + NBIN - 1) / NBIN;   // nodes per XCD bin

    k_prepAll<<<(81920 + 255) / 256, 256, 0, stream>>>(c1w, bt1, c2w, bt2, fc1w, btf, fc2w, btc, done);
    hipMemsetAsync(cur, 0, (size_t)n_nodes * sizeof(int), stream);

    k_fc0<<<(n_nodes * 32 + 255) / 256, 256, 0, stream>>>(x, fc0_w, fc0_b, c1u, h0, p, n_nodes);
    k_deg<<<NBIN * 512, 256, 0, stream>>>(eidx + ne, cur, ne, npb);
    k_scan_a<<<nblk, SCAN_BS, 0, stream>>>(cur, offa, blksum, done, n_nodes, nblk);
    k_scan_c<<<(n_nodes + 255) / 256, 256, 0, stream>>>(offa, cur, blksum, n_nodes);
    k_scatter<<<NBIN * 512, 256, 0, stream>>>(eidx, cur, ssrc, ne, npb);

    int ngrid = (n_nodes + 63) / 64;

    // conv1 fused: agg + GEMM (p1 computed in k_fc0)
    k_conv1<<<ngrid, 512, 0, stream>>>(h0, offa, ssrc, p, c1c, bt1, c1b, h1, n_nodes);

    // conv2 fused
    k_proj<C1_OUT><<<(n_nodes + 255) / 256, 256, 0, stream>>>(h1, c2u, p, n_nodes);
    k_conv2<<<ngrid, 512, 0, stream>>>(h1, offa, ssrc, p, c2c, bt2, c2b, h2, n_nodes);

    // fused head: fc1 + fc2 + log_softmax
    k_head<<<ngrid, 256, 0, stream>>>(h2, btf, fc1b, btc, fc2b, out, n_nodes);
}

// Round 20
// 247.357 us; speedup vs baseline: 1.0990x; 1.0990x over previous
//
#include <hip/hip_runtime.h>
#include <math.h>

#define F_IN 3
#define CH 32
#define HEADS 4
#define C1_OUT 64
#define C2_OUT 128
#define LIN 256
#define NCLS 25
#define NBIN 8

typedef __attribute__((ext_vector_type(8))) short bf16x8;
typedef __attribute__((ext_vector_type(4))) float f32x4;

__device__ __forceinline__ float elu_f(float x) {
    return x > 0.f ? x : (__expf(x) - 1.f);
}

__device__ __forceinline__ unsigned short f2bf(float f) {
    union { float f; unsigned int u; } v; v.f = f;
    unsigned int u = v.u + 0x7fffu + ((v.u >> 16) & 1u);
    return (unsigned short)(u >> 16);
}

__device__ __forceinline__ float bf2f(unsigned short u) {
    union { unsigned int u; float f; } v; v.u = ((unsigned int)u) << 16;
    return v.f;
}

__device__ __forceinline__ void unpackq(unsigned lo, unsigned hi, float& x, float& y,
                                        float& z, float& w) {
    x = bf2f((unsigned short)(lo & 0xffffu));
    y = bf2f((unsigned short)(lo >> 16));
    z = bf2f((unsigned short)(hi & 0xffffu));
    w = bf2f((unsigned short)(hi >> 16));
}

__device__ __forceinline__ void softmax4(const float* __restrict__ c,
                                         float& q0, float& q1, float& q2, float& q3) {
    float c0 = c[0], c1 = c[1], c2 = c[2], c3 = c[3];
    float mx = fmaxf(fmaxf(c0, c1), fmaxf(c2, c3));
    float e0 = __expf(c0 - mx), e1 = __expf(c1 - mx);
    float e2 = __expf(c2 - mx), e3 = __expf(c3 - mx);
    float inv = 1.f / (e0 + e1 + e2 + e3);
    q0 = e0 * inv; q1 = e1 * inv; q2 = e2 * inv; q3 = e3 * inv;
}

__device__ __forceinline__ void qslot(const float4* __restrict__ pp, float4 pd,
                                      float c0, float c1, float c2, float c3,
                                      int sx, bool valid,
                                      unsigned& qlo, unsigned& qhi) {
    float4 ps = pp[sx];
    float t0 = ps.x - pd.x + c0;
    float t1 = ps.y - pd.y + c1;
    float t2 = ps.z - pd.z + c2;
    float t3 = ps.w - pd.w + c3;
    float mx = fmaxf(fmaxf(t0, t1), fmaxf(t2, t3));
    float s0 = __expf(t0 - mx), s1 = __expf(t1 - mx);
    float s2 = __expf(t2 - mx), s3 = __expf(t3 - mx);
    float inv = 1.f / (s0 + s1 + s2 + s3);
    qlo = qhi = 0u;
    if (valid) {
        qlo = (unsigned)f2bf(s0 * inv) | ((unsigned)f2bf(s1 * inv) << 16);
        qhi = (unsigned)f2bf(s2 * inv) | ((unsigned)f2bf(s3 * inv) << 16);
    }
}

// ---------------- fc0 + proj1: wave per 2 nodes ----------------------------
__global__ __launch_bounds__(256) void k_fc0(
    const float* __restrict__ x, const float* __restrict__ w,
    const float* __restrict__ b, const float* __restrict__ u,
    unsigned short* __restrict__ h0, float* __restrict__ p, int n_nodes) {
    int wid = (blockIdx.x * blockDim.x + threadIdx.x) >> 6;
    int lane = threadIdx.x & 63;
    int half = lane >> 5, c = lane & 31;
    int node = wid * 2 + half;
    if (node >= n_nodes) return;
    float acc = b[c];
#pragma unroll
    for (int i = 0; i < F_IN; ++i) acc += x[node * F_IN + i] * w[i * CH + c];
    unsigned short hb = f2bf(elu_f(acc));
    h0[(size_t)node * CH + c] = hb;
    float hv = bf2f(hb);
    float a0 = hv * u[c * HEADS + 0];
    float a1 = hv * u[c * HEADS + 1];
    float a2 = hv * u[c * HEADS + 2];
    float a3 = hv * u[c * HEADS + 3];
#pragma unroll
    for (int m = 16; m >= 1; m >>= 1) {
        a0 += __shfl_xor(a0, m, 32); a1 += __shfl_xor(a1, m, 32);
        a2 += __shfl_xor(a2, m, 32); a3 += __shfl_xor(a3, m, 32);
    }
    if (c == 0) {
        p[node * 4 + 0] = a0; p[node * 4 + 1] = a1;
        p[node * 4 + 2] = a2; p[node * 4 + 3] = a3;
    }
}

// ---------------- degree count, XCD-binned by dst --------------------------
__global__ void k_deg(const int* __restrict__ dst, int* __restrict__ deg,
                      int ne, int npb) {
    int bin = blockIdx.x & (NBIN - 1);
    int blk = blockIdx.x >> 3;
    int nblk = gridDim.x >> 3;
    int per = (ne + nblk - 1) / nblk;
    int start = blk * per;
    int end = start + per < ne ? start + per : ne;
    int lo = bin * npb, hi = lo + npb;
    for (int e = start + threadIdx.x; e < end; e += blockDim.x) {
        int d = dst[e];
        if (d >= lo && d < hi) atomicAdd(&deg[d], 1);
    }
}

// ---------------- fused two-level exclusive scan (last-block top scan) -----
#define SCAN_BS 1024
__global__ __launch_bounds__(SCAN_BS) void k_scan_a(
    const int* __restrict__ deg, int* __restrict__ offa,
    int* __restrict__ blksum, int* __restrict__ done, int n, int nblk) {
    __shared__ int buf[SCAN_BS];
    __shared__ int lastflag;
    int tid = threadIdx.x;
    int i = blockIdx.x * SCAN_BS + tid;
    int v = (i < n) ? deg[i] : 0;
    buf[tid] = v;
    __syncthreads();
    for (int s = 1; s < SCAN_BS; s <<= 1) {
        int t = (tid >= s) ? buf[tid - s] : 0;
        __syncthreads();
        buf[tid] += t;
        __syncthreads();
    }
    if (i < n) offa[i] = buf[tid] - v;
    if (tid == SCAN_BS - 1) atomicExch(&blksum[blockIdx.x], buf[tid]);
    __threadfence();
    __syncthreads();
    if (tid == 0) lastflag = (atomicAdd(done, 1) == nblk - 1) ? 1 : 0;
    __syncthreads();
    if (lastflag) {
        int vv = (tid < nblk) ? atomicAdd(&blksum[tid], 0) : 0;
        buf[tid] = vv;
        __syncthreads();
        for (int s = 1; s < SCAN_BS; s <<= 1) {
            int t = (tid >= s) ? buf[tid - s] : 0;
            __syncthreads();
            buf[tid] += t;
            __syncthreads();
        }
        if (tid < nblk) blksum[tid] = buf[tid] - vv;
        if (tid == nblk - 1) offa[n] = buf[tid];
    }
}

__global__ void k_scan_c(int* __restrict__ offa, int* __restrict__ cur,
                         const int* __restrict__ blksum, int n) {
    int i = blockIdx.x * blockDim.x + threadIdx.x;
    if (i < n) {
        int o = offa[i] + blksum[i >> 10];
        offa[i] = o;
        cur[i] = o;
    }
}

// ---------------- scatter src only, XCD-binned ------------------------------
__global__ void k_scatter(const int* __restrict__ eidx, int* __restrict__ cur,
                          int* __restrict__ ssrc, int ne, int npb) {
    int bin = blockIdx.x & (NBIN - 1);
    int blk = blockIdx.x >> 3;
    int nblk = gridDim.x >> 3;
    int per = (ne + nblk - 1) / nblk;
    int start = blk * per;
    int end = start + per < ne ? start + per : ne;
    int lo = bin * npb, hi = lo + npb;
    for (int e = start + threadIdx.x; e < end; e += blockDim.x) {
        int d = eidx[ne + e];
        if (d >= lo && d < hi) {
            int s = eidx[e];
            int pos = atomicAdd(&cur[d], 1);
            ssrc[pos] = s;
        }
    }
}

// ---------------- per-node head projection (conv2 only) --------------------
template<int IN>
__global__ void k_proj(const unsigned short* __restrict__ h,
                       const float* __restrict__ u,
                       float* __restrict__ p, int n_nodes) {
    int node = blockIdx.x * blockDim.x + threadIdx.x;
    if (node >= n_nodes) return;
    const unsigned short* hr = h + (size_t)node * IN;
    float a0 = 0.f, a1 = 0.f, a2 = 0.f, a3 = 0.f;
#pragma unroll
    for (int kb = 0; kb < IN; kb += 8) {
        uint4 uu = *(const uint4*)(hr + kb);
        unsigned int ws_[4] = {uu.x, uu.y, uu.z, uu.w};
#pragma unroll
        for (int j = 0; j < 4; ++j) {
            float vlo = bf2f((unsigned short)(ws_[j] & 0xffffu));
            float vhi = bf2f((unsigned short)(ws_[j] >> 16));
            int k0 = kb + j * 2, k1 = kb + j * 2 + 1;
            a0 = fmaf(vlo, u[k0 * HEADS + 0], a0); a0 = fmaf(vhi, u[k1 * HEADS + 0], a0);
            a1 = fmaf(vlo, u[k0 * HEADS + 1], a1); a1 = fmaf(vhi, u[k1 * HEADS + 1], a1);
            a2 = fmaf(vlo, u[k0 * HEADS + 2], a2); a2 = fmaf(vhi, u[k1 * HEADS + 2], a2);
            a3 = fmaf(vlo, u[k0 * HEADS + 3], a3); a3 = fmaf(vhi, u[k1 * HEADS + 3], a3);
        }
    }
    p[node * 4 + 0] = a0; p[node * 4 + 1] = a1;
    p[node * 4 + 2] = a2; p[node * 4 + 3] = a3;
}

// ---------------- merged weight prep + done-counter reset ------------------
__global__ void k_prepAll(const float* __restrict__ W1, unsigned short* __restrict__ B1,
                          const float* __restrict__ W2, unsigned short* __restrict__ B2,
                          const float* __restrict__ Wf, unsigned short* __restrict__ Bf,
                          const float* __restrict__ Wc, unsigned short* __restrict__ Bc,
                          int* __restrict__ done) {
    int idx = blockIdx.x * blockDim.x + threadIdx.x;
    if (idx == 0) *done = 0;
    if (idx < 8192) {                       // conv1: K=128 M=64 IN=32
        int o = idx / 128, j = idx % 128;
        int hh = j / 32, k = j % 32;
        B1[idx] = f2bf(W1[k * (HEADS * 64) + hh * 64 + o]);
    } else if (idx < 40960) {               // conv2: K=256 M=128 IN=64
        int i = idx - 8192;
        int o = i / 256, j = i % 256;
        int hh = j / 64, k = j % 64;
        B2[i] = f2bf(W2[k * (HEADS * 128) + hh * 128 + o]);
    } else if (idx < 73728) {               // fc1: K=128 M=256 transpose
        int i = idx - 40960;
        int o = i / 128, j = i % 128;
        Bf[i] = f2bf(Wf[j * 256 + o]);
    } else if (idx < 81920) {               // fc2: pad 25->32, K=256
        int i = idx - 73728;
        int o = i >> 8, k = i & 255;
        Bc[i] = f2bf(o < NCLS ? Wc[k * NCLS + o] : 0.f);
    }
}

// ---------------- conv1 gather-aggregate, fused lane-parallel q ------------
__global__ __launch_bounds__(256) void k_agg1(
    const unsigned short* __restrict__ h, const int* __restrict__ offa,
    const int* __restrict__ ssrc, const float* __restrict__ p,
    const float* __restrict__ cvec, unsigned short* __restrict__ arow,
    int n_nodes) {
    int wid = (blockIdx.x * blockDim.x + threadIdx.x) >> 6;
    int lane = threadIdx.x & 63;
    if (wid >= n_nodes) return;
    int half = lane >> 5, ch = lane & 31;
    int slot = lane & 7, sbase = lane & 56;
    int e0 = __builtin_amdgcn_readfirstlane(offa[wid]);
    int e1 = __builtin_amdgcn_readfirstlane(offa[wid + 1]);
    const float4* pp = (const float4*)p;
    float4 pd = pp[wid];
    float c0 = cvec[0], c1 = cvec[1], c2 = cvec[2], c3 = cvec[3];
    float a0 = 0.f, a1 = 0.f, a2 = 0.f, a3 = 0.f;
    for (int e = e0; e < e1; e += 8) {
        int ee = e + slot;
        int ec = ee < e1 ? ee : e0;
        int sx = ssrc[ec];
        unsigned qlo, qhi;
        qslot(pp, pd, c0, c1, c2, c3, sx, ee < e1, qlo, qhi);
#pragma unroll
        for (int m = 0; m < 4; ++m) {
            int src = sbase + 2 * m + half;
            int sj = __shfl(sx, src, 64);
            unsigned lo = (unsigned)__shfl((int)qlo, src, 64);
            unsigned hi = (unsigned)__shfl((int)qhi, src, 64);
            float xj = bf2f(h[(size_t)sj * CH + ch]);
            float qx, qy, qz, qw;
            unpackq(lo, hi, qx, qy, qz, qw);
            a0 = fmaf(qx, xj, a0); a1 = fmaf(qy, xj, a1);
            a2 = fmaf(qz, xj, a2); a3 = fmaf(qw, xj, a3);
        }
    }
    a0 += __shfl_xor(a0, 32); a1 += __shfl_xor(a1, 32);
    a2 += __shfl_xor(a2, 32); a3 += __shfl_xor(a3, 32);
    if (half == 0) {
        float qc0, qc1, qc2, qc3;
        softmax4(cvec, qc0, qc1, qc2, qc3);
        float xi = bf2f(h[(size_t)wid * CH + ch]);
        a0 = fmaf(qc0, xi, a0); a1 = fmaf(qc1, xi, a1);
        a2 = fmaf(qc2, xi, a2); a3 = fmaf(qc3, xi, a3);
        float inv = 1.f / (float)(e1 - e0 + 1);
        arow[(size_t)wid * 128 + 0 * CH + ch] = f2bf(a0 * inv);
        arow[(size_t)wid * 128 + 1 * CH + ch] = f2bf(a1 * inv);
        arow[(size_t)wid * 128 + 2 * CH + ch] = f2bf(a2 * inv);
        arow[(size_t)wid * 128 + 3 * CH + ch] = f2bf(a3 * inv);
    }
}

// ---------------- conv2 gather-aggregate, fused lane-parallel q ------------
__global__ __launch_bounds__(256) void k_agg2(
    const unsigned short* __restrict__ h, const int* __restrict__ offa,
    const int* __restrict__ ssrc, const float* __restrict__ p,
    const float* __restrict__ cvec, unsigned short* __restrict__ arow,
    int n_nodes) {
    int wid = (blockIdx.x * blockDim.x + threadIdx.x) >> 6;
    int lane = threadIdx.x & 63;
    if (wid >= n_nodes) return;
    int slot = lane & 7, sbase = lane & 56;
    int e0 = __builtin_amdgcn_readfirstlane(offa[wid]);
    int e1 = __builtin_amdgcn_readfirstlane(offa[wid + 1]);
    const float4* pp = (const float4*)p;
    float4 pd = pp[wid];
    float c0 = cvec[0], c1 = cvec[1], c2 = cvec[2], c3 = cvec[3];
    float a0 = 0.f, a1 = 0.f, a2 = 0.f, a3 = 0.f;
    for (int e = e0; e < e1; e += 8) {
        int ee = e + slot;
        int ec = ee < e1 ? ee : e0;
        int sx = ssrc[ec];
        unsigned qlo, qhi;
        qslot(pp, pd, c0, c1, c2, c3, sx, ee < e1, qlo, qhi);
#pragma unroll
        for (int j = 0; j < 8; ++j) {
            int src = sbase + j;
            int sj = __shfl(sx, src, 64);
            unsigned lo = (unsigned)__shfl((int)qlo, src, 64);
            unsigned hi = (unsigned)__shfl((int)qhi, src, 64);
            float xj = bf2f(h[(size_t)sj * C1_OUT + lane]);
            float qx, qy, qz, qw;
            unpackq(lo, hi, qx, qy, qz, qw);
            a0 = fmaf(qx, xj, a0); a1 = fmaf(qy, xj, a1);
            a2 = fmaf(qz, xj, a2); a3 = fmaf(qw, xj, a3);
        }
    }
    float qc0, qc1, qc2, qc3;
    softmax4(cvec, qc0, qc1, qc2, qc3);
    float xi = bf2f(h[(size_t)wid * C1_OUT + lane]);
    a0 = fmaf(qc0, xi, a0); a1 = fmaf(qc1, xi, a1);
    a2 = fmaf(qc2, xi, a2); a3 = fmaf(qc3, xi, a3);
    float inv = 1.f / (float)(e1 - e0 + 1);
    arow[(size_t)wid * 256 + 0 * C1_OUT + lane] = f2bf(a0 * inv);
    arow[(size_t)wid * 256 + 1 * C1_OUT + lane] = f2bf(a1 * inv);
    arow[(size_t)wid * 256 + 2 * C1_OUT + lane] = f2bf(a2 * inv);
    arow[(size_t)wid * 256 + 3 * C1_OUT + lane] = f2bf(a3 * inv);
}

// ---------------- MFMA GEMM: D = bf16(elu(A @ Bt^T + bias)), A bf16 --------
template<int K, int M>
__global__ __launch_bounds__(256) void k_mgemm(
    const unsigned short* __restrict__ A, const unsigned short* __restrict__ Bt,
    const float* __restrict__ bias, unsigned short* __restrict__ D, int n) {
    constexpr int CPW = M / 4;
    constexpr int NCF = CPW / 16;
    constexpr int NKC = K / 32;
    __shared__ unsigned short Al[64 * K];
    int tid = threadIdx.x;
    int w = tid >> 6, l = tid & 63;
    int l16 = l & 15, l4 = l >> 4;
    int rowbase = blockIdx.x * 64;

    bf16x8 bfr[NCF][NKC];
#pragma unroll
    for (int c = 0; c < NCF; ++c)
#pragma unroll
        for (int t = 0; t < NKC; ++t) {
            int col = w * CPW + c * 16 + l16;
            int k = t * 32 + l4 * 8;
            bfr[c][t] = *(const bf16x8*)(Bt + (size_t)col * K + k);
        }

    constexpr int CHUNKS = 64 * K / 8;
    for (int idx = tid; idx < CHUNKS; idx += 256) {
        int row = idx / (K / 8);
        int kb = (idx % (K / 8)) * 8;
        int grow = rowbase + row;
        uint4 u;
        if (grow < n) u = *(const uint4*)(A + (size_t)grow * K + kb);
        else          u.x = u.y = u.z = u.w = 0u;
        int byte = ((row * K + kb) * 2) ^ ((row & 7) << 4);
        *(uint4*)((char*)Al + byte) = u;
    }
    __syncthreads();

#pragma unroll
    for (int r = 0; r < 4; ++r) {
        bf16x8 af[NKC];
        int row = r * 16 + l16;
#pragma unroll
        for (int t = 0; t < NKC; ++t) {
            int byte = ((row * K + t * 32 + l4 * 8) * 2) ^ ((row & 7) << 4);
            af[t] = *(bf16x8*)((char*)Al + byte);
        }
#pragma unroll
        for (int c = 0; c < NCF; ++c) {
            f32x4 acc = {0.f, 0.f, 0.f, 0.f};
#pragma unroll
            for (int t = 0; t < NKC; ++t)
                acc = __builtin_amdgcn_mfma_f32_16x16x32_bf16(af[t], bfr[c][t], acc, 0, 0, 0);
            int col = w * CPW + c * 16 + l16;
            float bv = bias[col];
#pragma unroll
            for (int j = 0; j < 4; ++j) {
                int grow = rowbase + r * 16 + l4 * 4 + j;
                if (grow < n)
                    D[(size_t)grow * M + col] = f2bf(elu_f(acc[j] + bv));
            }
        }
    }
}

// ---------------- fused head: fc1 in LDS -> fc2 + log_softmax --------------
__global__ __launch_bounds__(256) void k_head(
    const unsigned short* __restrict__ A, const unsigned short* __restrict__ Btf,
    const float* __restrict__ bias1, const unsigned short* __restrict__ Btc,
    const float* __restrict__ bias2, float* __restrict__ out, int n) {
    __shared__ unsigned short Al[64 * 128];   // 16 KB
    __shared__ unsigned short Hl[64 * 256];   // 32 KB
    int tid = threadIdx.x;
    int w = tid >> 6, l = tid & 63;
    int l16 = l & 15, l4 = l >> 4;
    int rowbase = blockIdx.x * 64;

    bf16x8 bfr[4][4];
#pragma unroll
    for (int c = 0; c < 4; ++c)
#pragma unroll
        for (int t = 0; t < 4; ++t) {
            int col = w * 64 + c * 16 + l16;
            int k = t * 32 + l4 * 8;
            bfr[c][t] = *(const bf16x8*)(Btf + (size_t)col * 128 + k);
        }

    for (int idx = tid; idx < 1024; idx += 256) {
        int row = idx >> 4;
        int kb = (idx & 15) * 8;
        int grow = rowbase + row;
        uint4 u;
        if (grow < n) u = *(const uint4*)(A + (size_t)grow * 128 + kb);
        else          u.x = u.y = u.z = u.w = 0u;
        int byte = ((row * 128 + kb) * 2) ^ ((row & 7) << 4);
        *(uint4*)((char*)Al + byte) = u;
    }
    __syncthreads();

#pragma unroll
    for (int r = 0; r < 4; ++r) {
        bf16x8 af[4];
        int row = r * 16 + l16;
#pragma unroll
        for (int t = 0; t < 4; ++t) {
            int byte = ((row * 128 + t * 32 + l4 * 8) * 2) ^ ((row & 7) << 4);
            af[t] = *(bf16x8*)((char*)Al + byte);
        }
#pragma unroll
        for (int c = 0; c < 4; ++c) {
            f32x4 acc = {0.f, 0.f, 0.f, 0.f};
#pragma unroll
            for (int t = 0; t < 4; ++t)
                acc = __builtin_amdgcn_mfma_f32_16x16x32_bf16(af[t], bfr[c][t], acc, 0, 0, 0);
            int col = w * 64 + c * 16 + l16;
            float bv = bias1[col];
#pragma unroll
            for (int j = 0; j < 4; ++j) {
                int lrow = r * 16 + l4 * 4 + j;
                unsigned short v = f2bf(elu_f(acc[j] + bv));
                int byte = ((lrow * 256 + col) * 2) ^ ((lrow & 7) << 4);
                *(unsigned short*)((char*)Hl + byte) = v;
            }
        }
    }
    __syncthreads();

    bf16x8 b0[8], b1[8];
#pragma unroll
    for (int t = 0; t < 8; ++t) {
        int k = t * 32 + l4 * 8;
        b0[t] = *(const bf16x8*)(Btc + (size_t)l16 * LIN + k);
        b1[t] = *(const bf16x8*)(Btc + (size_t)(16 + l16) * LIN + k);
    }
    float bb0 = bias2[l16];
    bool hi_ok = (l16 < NCLS - 16);
    float bb1 = hi_ok ? bias2[16 + l16] : 0.f;

    int lrow = w * 16 + l16;
    bf16x8 af[8];
#pragma unroll
    for (int t = 0; t < 8; ++t) {
        int byte = ((lrow * 256 + t * 32 + l4 * 8) * 2) ^ ((lrow & 7) << 4);
        af[t] = *(bf16x8*)((char*)Hl + byte);
    }
    f32x4 acc0 = {0.f, 0.f, 0.f, 0.f}, acc1 = {0.f, 0.f, 0.f, 0.f};
#pragma unroll
    for (int t = 0; t < 8; ++t) {
        acc0 = __builtin_amdgcn_mfma_f32_16x16x32_bf16(af[t], b0[t], acc0, 0, 0, 0);
        acc1 = __builtin_amdgcn_mfma_f32_16x16x32_bf16(af[t], b1[t], acc1, 0, 0, 0);
    }
#pragma unroll
    for (int j = 0; j < 4; ++j) {
        float v0 = acc0[j] + bb0;
        float v1 = acc1[j] + bb1;
        float m = fmaxf(v0, hi_ok ? v1 : -1e30f);
#pragma unroll
        for (int msk = 8; msk >= 1; msk >>= 1)
            m = fmaxf(m, __shfl_xor(m, msk, 16));
        float s = __expf(v0 - m) + (hi_ok ? __expf(v1 - m) : 0.f);
#pragma unroll
        for (int msk = 8; msk >= 1; msk >>= 1)
            s += __shfl_xor(s, msk, 16);
        float lse = m + __logf(s);
        int ro = rowbase + w * 16 + l4 * 4 + j;
        if (ro < n) {
            out[(size_t)ro * NCLS + l16] = v0 - lse;
            if (hi_ok) out[(size_t)ro * NCLS + 16 + l16] = v1 - lse;
        }
    }
}

extern "C" void kernel_launch(void* const* d_in, const int* in_sizes, int n_in,
                              void* d_out, int out_size, void* d_ws, size_t ws_size,
                              hipStream_t stream) {
    const float* x     = (const float*)d_in[0];
    const int*   eidx  = (const int*)d_in[1];
    const float* fc0_w = (const float*)d_in[2];
    const float* fc0_b = (const float*)d_in[3];
    const float* c1w   = (const float*)d_in[4];
    const float* c1u   = (const float*)d_in[5];
    const float* c1c   = (const float*)d_in[6];
    const float* c1b   = (const float*)d_in[7];
    const float* c2w   = (const float*)d_in[8];
    const float* c2u   = (const float*)d_in[9];
    const float* c2c   = (const float*)d_in[10];
    const float* c2b   = (const float*)d_in[11];
    const float* fc1w  = (const float*)d_in[12];
    const float* fc1b  = (const float*)d_in[13];
    const float* fc2w  = (const float*)d_in[14];
    const float* fc2b  = (const float*)d_in[15];

    int n_nodes = in_sizes[0] / F_IN;   // 50000
    int ne      = in_sizes[1] / 2;      // 800000

    // ---- workspace layout (float units) — fully un-aliased ----
    auto align4 = [](size_t v) { return (v + 3) & ~(size_t)3; };
    float* ws = (float*)d_ws;
    size_t t = 0;
    size_t off_o = t; t += align4((size_t)n_nodes + 1);
    size_t cur_o = t; t += align4((size_t)n_nodes);
    size_t blk_o = t; t += 64;
    size_t don_o = t; t += 4;
    size_t p_o   = t; t += align4((size_t)n_nodes * 4);
    size_t h0_o  = t; t += align4((size_t)n_nodes * 16);   // n*32 bf16
    size_t h1_o  = t; t += align4((size_t)n_nodes * 32);   // n*64 bf16
    size_t h2_o  = t; t += align4((size_t)n_nodes * 64);   // n*128 bf16
    size_t ar_o  = t; t += align4((size_t)n_nodes * 128);  // arow1|arow2 (n*256 bf16)
    size_t ss_o  = t; t += align4((size_t)ne);             // ssrc: int
    size_t bt1_o = t; t += 4096;
    size_t bt2_o = t; t += 16384;
    size_t btf_o = t; t += 16384;
    size_t btc_o = t; t += 4096;

    int*    offa   = (int*)(ws + off_o);
    int*    cur    = (int*)(ws + cur_o);
    int*    blksum = (int*)(ws + blk_o);
    int*    done   = (int*)(ws + don_o);
    float*  p      = ws + p_o;
    unsigned short* h0    = (unsigned short*)(ws + h0_o);
    unsigned short* h1    = (unsigned short*)(ws + h1_o);
    unsigned short* h2    = (unsigned short*)(ws + h2_o);
    unsigned short* arow1 = (unsigned short*)(ws + ar_o);
    unsigned short* arow2 = (unsigned short*)(ws + ar_o);
    int*    ssrc   = (int*)(ws + ss_o);
    unsigned short* bt1 = (unsigned short*)(ws + bt1_o);
    unsigned short* bt2 = (unsigned short*)(ws + bt2_o);
    unsigned short* btf = (unsigned short*)(ws + btf_o);
    unsigned short* btc = (unsigned short*)(ws + btc_o);
    float*  out    = (float*)d_out;

    int nblk = (n_nodes + SCAN_BS - 1) / SCAN_BS;
    int npb  = (n_nodes + NBIN - 1) / NBIN;   // nodes per XCD bin

    k_prepAll<<<(81920 + 255) / 256, 256, 0, stream>>>(c1w, bt1, c2w, bt2, fc1w, btf, fc2w, btc, done);
    hipMemsetAsync(cur, 0, (size_t)n_nodes * sizeof(int), stream);

    k_fc0<<<(n_nodes * 32 + 255) / 256, 256, 0, stream>>>(x, fc0_w, fc0_b, c1u, h0, p, n_nodes);
    k_deg<<<NBIN * 512, 256, 0, stream>>>(eidx + ne, cur, ne, npb);
    k_scan_a<<<nblk, SCAN_BS, 0, stream>>>(cur, offa, blksum, done, n_nodes, nblk);
    k_scan_c<<<(n_nodes + 255) / 256, 256, 0, stream>>>(offa, cur, blksum, n_nodes);
    k_scatter<<<NBIN * 512, 256, 0, stream>>>(eidx, cur, ssrc, ne, npb);

    int ngrid = (n_nodes + 63) / 64;

    // conv1 (p1 computed in k_fc0)
    k_agg1<<<(n_nodes * 64 + 255) / 256, 256, 0, stream>>>(h0, offa, ssrc, p, c1c, arow1, n_nodes);
    k_mgemm<128, 64><<<ngrid, 256, 0, stream>>>(arow1, bt1, c1b, h1, n_nodes);

    // conv2
    k_proj<C1_OUT><<<(n_nodes + 255) / 256, 256, 0, stream>>>(h1, c2u, p, n_nodes);
    k_agg2<<<(n_nodes * 64 + 255) / 256, 256, 0, stream>>>(h1, offa, ssrc, p, c2c, arow2, n_nodes);
    k_mgemm<256, 128><<<ngrid, 256, 0, stream>>>(arow2, bt2, c2b, h2, n_nodes);

    // fused head: fc1 + fc2 + log_softmax
    k_head<<<ngrid, 256, 0, stream>>>(h2, btf, fc1b, btc, fc2b, out, n_nodes);
}

// Round 21
// 233.957 us; speedup vs baseline: 1.1619x; 1.0573x over previous
//
#include <hip/hip_runtime.h>
#include <math.h>

#define F_IN 3
#define CH 32
#define HEADS 4
#define C1_OUT 64
#define C2_OUT 128
#define LIN 256
#define NCLS 25
#define NBIN 8

typedef __attribute__((ext_vector_type(8))) short bf16x8;
typedef __attribute__((ext_vector_type(4))) float f32x4;

__device__ __forceinline__ float elu_f(float x) {
    return x > 0.f ? x : (__expf(x) - 1.f);
}

__device__ __forceinline__ unsigned short f2bf(float f) {
    union { float f; unsigned int u; } v; v.f = f;
    unsigned int u = v.u + 0x7fffu + ((v.u >> 16) & 1u);
    return (unsigned short)(u >> 16);
}

__device__ __forceinline__ float bf2f(unsigned short u) {
    union { unsigned int u; float f; } v; v.u = ((unsigned int)u) << 16;
    return v.f;
}

__device__ __forceinline__ void unpackq(unsigned lo, unsigned hi, float& x, float& y,
                                        float& z, float& w) {
    x = bf2f((unsigned short)(lo & 0xffffu));
    y = bf2f((unsigned short)(lo >> 16));
    z = bf2f((unsigned short)(hi & 0xffffu));
    w = bf2f((unsigned short)(hi >> 16));
}

__device__ __forceinline__ void softmax4(const float* __restrict__ c,
                                         float& q0, float& q1, float& q2, float& q3) {
    float c0 = c[0], c1 = c[1], c2 = c[2], c3 = c[3];
    float mx = fmaxf(fmaxf(c0, c1), fmaxf(c2, c3));
    float e0 = __expf(c0 - mx), e1 = __expf(c1 - mx);
    float e2 = __expf(c2 - mx), e3 = __expf(c3 - mx);
    float inv = 1.f / (e0 + e1 + e2 + e3);
    q0 = e0 * inv; q1 = e1 * inv; q2 = e2 * inv; q3 = e3 * inv;
}

// per-lane fused q: compute q for edge slot (lane&7); qlo/qhi zeroed if invalid
__device__ __forceinline__ void qslot(const float4* __restrict__ pp, float4 pd,
                                      float c0, float c1, float c2, float c3,
                                      int sx, bool valid,
                                      unsigned& qlo, unsigned& qhi) {
    float4 ps = pp[sx];
    float t0 = ps.x - pd.x + c0;
    float t1 = ps.y - pd.y + c1;
    float t2 = ps.z - pd.z + c2;
    float t3 = ps.w - pd.w + c3;
    float mx = fmaxf(fmaxf(t0, t1), fmaxf(t2, t3));
    float s0 = __expf(t0 - mx), s1 = __expf(t1 - mx);
    float s2 = __expf(t2 - mx), s3 = __expf(t3 - mx);
    float inv = 1.f / (s0 + s1 + s2 + s3);
    qlo = qhi = 0u;
    if (valid) {
        qlo = (unsigned)f2bf(s0 * inv) | ((unsigned)f2bf(s1 * inv) << 16);
        qhi = (unsigned)f2bf(s2 * inv) | ((unsigned)f2bf(s3 * inv) << 16);
    }
}

// ---------------- fc0 + proj1: wave per 2 nodes ----------------------------
__global__ __launch_bounds__(256) void k_fc0(
    const float* __restrict__ x, const float* __restrict__ w,
    const float* __restrict__ b, const float* __restrict__ u,
    unsigned short* __restrict__ h0, float* __restrict__ p, int n_nodes) {
    int wid = (blockIdx.x * blockDim.x + threadIdx.x) >> 6;
    int lane = threadIdx.x & 63;
    int half = lane >> 5, c = lane & 31;
    int node = wid * 2 + half;
    if (node >= n_nodes) return;
    float acc = b[c];
#pragma unroll
    for (int i = 0; i < F_IN; ++i) acc += x[node * F_IN + i] * w[i * CH + c];
    unsigned short hb = f2bf(elu_f(acc));
    h0[(size_t)node * CH + c] = hb;
    float hv = bf2f(hb);
    float a0 = hv * u[c * HEADS + 0];
    float a1 = hv * u[c * HEADS + 1];
    float a2 = hv * u[c * HEADS + 2];
    float a3 = hv * u[c * HEADS + 3];
#pragma unroll
    for (int m = 16; m >= 1; m >>= 1) {
        a0 += __shfl_xor(a0, m, 32); a1 += __shfl_xor(a1, m, 32);
        a2 += __shfl_xor(a2, m, 32); a3 += __shfl_xor(a3, m, 32);
    }
    if (c == 0) {
        p[node * 4 + 0] = a0; p[node * 4 + 1] = a1;
        p[node * 4 + 2] = a2; p[node * 4 + 3] = a3;
    }
}

// ---------------- degree count, XCD-binned by dst --------------------------
__global__ void k_deg(const int* __restrict__ dst, int* __restrict__ deg,
                      int ne, int npb) {
    int bin = blockIdx.x & (NBIN - 1);
    int blk = blockIdx.x >> 3;
    int nblk = gridDim.x >> 3;
    int per = (ne + nblk - 1) / nblk;
    int start = blk * per;
    int end = start + per < ne ? start + per : ne;
    int lo = bin * npb, hi = lo + npb;
    for (int e = start + threadIdx.x; e < end; e += blockDim.x) {
        int d = dst[e];
        if (d >= lo && d < hi) atomicAdd(&deg[d], 1);
    }
}

// ---------------- two-level exclusive scan ---------------------------------
#define SCAN_BS 1024
__global__ __launch_bounds__(SCAN_BS) void k_scan_a(
    const int* __restrict__ deg, int* __restrict__ offa,
    int* __restrict__ blksum, int n) {
    __shared__ int buf[SCAN_BS];
    int tid = threadIdx.x;
    int i = blockIdx.x * SCAN_BS + tid;
    int v = (i < n) ? deg[i] : 0;
    buf[tid] = v;
    __syncthreads();
    for (int s = 1; s < SCAN_BS; s <<= 1) {
        int t = (tid >= s) ? buf[tid - s] : 0;
        __syncthreads();
        buf[tid] += t;
        __syncthreads();
    }
    if (i < n) offa[i] = buf[tid] - v;
    if (tid == SCAN_BS - 1) blksum[blockIdx.x] = buf[tid];
}

__global__ void k_scan_b(int* __restrict__ blksum, int* __restrict__ offa,
                         int nblk, int n) {
    int tid = threadIdx.x;
    int orig = (tid < nblk) ? blksum[tid] : 0;
    int v = orig;
#pragma unroll
    for (int s = 1; s < 64; s <<= 1) {
        int t = __shfl_up(v, s, 64);
        if (tid >= s) v += t;
    }
    if (tid < nblk) blksum[tid] = v - orig;
    if (tid == nblk - 1) offa[n] = v;
}

__global__ void k_scan_c(int* __restrict__ offa, int* __restrict__ cur,
                         const int* __restrict__ blksum, int n) {
    int i = blockIdx.x * blockDim.x + threadIdx.x;
    if (i < n) {
        int o = offa[i] + blksum[i >> 10];
        offa[i] = o;
        cur[i] = o;
    }
}

// ---------------- scatter src only (dst never read downstream) -------------
__global__ void k_scatter(const int* __restrict__ eidx, int* __restrict__ cur,
                          int* __restrict__ ssrc, int ne, int npb) {
    int bin = blockIdx.x & (NBIN - 1);
    int blk = blockIdx.x >> 3;
    int nblk = gridDim.x >> 3;
    int per = (ne + nblk - 1) / nblk;
    int start = blk * per;
    int end = start + per < ne ? start + per : ne;
    int lo = bin * npb, hi = lo + npb;
    for (int e = start + threadIdx.x; e < end; e += blockDim.x) {
        int d = eidx[ne + e];
        if (d >= lo && d < hi) {
            int s = eidx[e];
            int pos = atomicAdd(&cur[d], 1);
            ssrc[pos] = s;
        }
    }
}

// ---------------- per-node head projection (conv2 only) --------------------
template<int IN>
__global__ void k_proj(const unsigned short* __restrict__ h,
                       const float* __restrict__ u,
                       float* __restrict__ p, int n_nodes) {
    int node = blockIdx.x * blockDim.x + threadIdx.x;
    if (node >= n_nodes) return;
    const unsigned short* hr = h + (size_t)node * IN;
    float a0 = 0.f, a1 = 0.f, a2 = 0.f, a3 = 0.f;
#pragma unroll
    for (int kb = 0; kb < IN; kb += 8) {
        uint4 uu = *(const uint4*)(hr + kb);
        unsigned int ws_[4] = {uu.x, uu.y, uu.z, uu.w};
#pragma unroll
        for (int j = 0; j < 4; ++j) {
            float vlo = bf2f((unsigned short)(ws_[j] & 0xffffu));
            float vhi = bf2f((unsigned short)(ws_[j] >> 16));
            int k0 = kb + j * 2, k1 = kb + j * 2 + 1;
            a0 = fmaf(vlo, u[k0 * HEADS + 0], a0); a0 = fmaf(vhi, u[k1 * HEADS + 0], a0);
            a1 = fmaf(vlo, u[k0 * HEADS + 1], a1); a1 = fmaf(vhi, u[k1 * HEADS + 1], a1);
            a2 = fmaf(vlo, u[k0 * HEADS + 2], a2); a2 = fmaf(vhi, u[k1 * HEADS + 2], a2);
            a3 = fmaf(vlo, u[k0 * HEADS + 3], a3); a3 = fmaf(vhi, u[k1 * HEADS + 3], a3);
        }
    }
    p[node * 4 + 0] = a0; p[node * 4 + 1] = a1;
    p[node * 4 + 2] = a2; p[node * 4 + 3] = a3;
}

// ---------------- conv1 gather-aggregate, fused lane-parallel q ------------
__global__ __launch_bounds__(256) void k_agg1(
    const unsigned short* __restrict__ h, const int* __restrict__ offa,
    const int* __restrict__ ssrc, const float* __restrict__ p,
    const float* __restrict__ cvec, unsigned short* __restrict__ arow,
    int n_nodes) {
    int wid = (blockIdx.x * blockDim.x + threadIdx.x) >> 6;
    int lane = threadIdx.x & 63;
    if (wid >= n_nodes) return;
    int half = lane >> 5, ch = lane & 31;
    int slot = lane & 7, sbase = lane & 56;
    int e0 = __builtin_amdgcn_readfirstlane(offa[wid]);
    int e1 = __builtin_amdgcn_readfirstlane(offa[wid + 1]);
    const float4* pp = (const float4*)p;
    float4 pd = pp[wid];
    float c0 = cvec[0], c1 = cvec[1], c2 = cvec[2], c3 = cvec[3];
    float a0 = 0.f, a1 = 0.f, a2 = 0.f, a3 = 0.f;
    for (int e = e0; e < e1; e += 8) {
        int ee = e + slot;
        int ec = ee < e1 ? ee : e0;
        int sx = ssrc[ec];
        unsigned qlo, qhi;
        qslot(pp, pd, c0, c1, c2, c3, sx, ee < e1, qlo, qhi);
#pragma unroll
        for (int m = 0; m < 4; ++m) {
            int src = sbase + 2 * m + half;
            int sj = __shfl(sx, src, 64);
            unsigned lo = (unsigned)__shfl((int)qlo, src, 64);
            unsigned hi = (unsigned)__shfl((int)qhi, src, 64);
            float xj = bf2f(h[(size_t)sj * CH + ch]);
            float qx, qy, qz, qw;
            unpackq(lo, hi, qx, qy, qz, qw);
            a0 = fmaf(qx, xj, a0); a1 = fmaf(qy, xj, a1);
            a2 = fmaf(qz, xj, a2); a3 = fmaf(qw, xj, a3);
        }
    }
    a0 += __shfl_xor(a0, 32); a1 += __shfl_xor(a1, 32);
    a2 += __shfl_xor(a2, 32); a3 += __shfl_xor(a3, 32);
    if (half == 0) {
        float qc0, qc1, qc2, qc3;
        softmax4(cvec, qc0, qc1, qc2, qc3);
        float xi = bf2f(h[(size_t)wid * CH + ch]);
        a0 = fmaf(qc0, xi, a0); a1 = fmaf(qc1, xi, a1);
        a2 = fmaf(qc2, xi, a2); a3 = fmaf(qc3, xi, a3);
        float inv = 1.f / (float)(e1 - e0 + 1);
        arow[(size_t)wid * 128 + 0 * CH + ch] = f2bf(a0 * inv);
        arow[(size_t)wid * 128 + 1 * CH + ch] = f2bf(a1 * inv);
        arow[(size_t)wid * 128 + 2 * CH + ch] = f2bf(a2 * inv);
        arow[(size_t)wid * 128 + 3 * CH + ch] = f2bf(a3 * inv);
    }
}

// ---------------- conv2 gather-aggregate, fused lane-parallel q ------------
__global__ __launch_bounds__(256) void k_agg2(
    const unsigned short* __restrict__ h, const int* __restrict__ offa,
    const int* __restrict__ ssrc, const float* __restrict__ p,
    const float* __restrict__ cvec, unsigned short* __restrict__ arow,
    int n_nodes) {
    int wid = (blockIdx.x * blockDim.x + threadIdx.x) >> 6;
    int lane = threadIdx.x & 63;
    if (wid >= n_nodes) return;
    int slot = lane & 7, sbase = lane & 56;
    int e0 = __builtin_amdgcn_readfirstlane(offa[wid]);
    int e1 = __builtin_amdgcn_readfirstlane(offa[wid + 1]);
    const float4* pp = (const float4*)p;
    float4 pd = pp[wid];
    float c0 = cvec[0], c1 = cvec[1], c2 = cvec[2], c3 = cvec[3];
    float a0 = 0.f, a1 = 0.f, a2 = 0.f, a3 = 0.f;
    for (int e = e0; e < e1; e += 8) {
        int ee = e + slot;
        int ec = ee < e1 ? ee : e0;
        int sx = ssrc[ec];
        unsigned qlo, qhi;
        qslot(pp, pd, c0, c1, c2, c3, sx, ee < e1, qlo, qhi);
#pragma unroll
        for (int j = 0; j < 8; ++j) {
            int src = sbase + j;
            int sj = __shfl(sx, src, 64);
            unsigned lo = (unsigned)__shfl((int)qlo, src, 64);
            unsigned hi = (unsigned)__shfl((int)qhi, src, 64);
            float xj = bf2f(h[(size_t)sj * C1_OUT + lane]);
            float qx, qy, qz, qw;
            unpackq(lo, hi, qx, qy, qz, qw);
            a0 = fmaf(qx, xj, a0); a1 = fmaf(qy, xj, a1);
            a2 = fmaf(qz, xj, a2); a3 = fmaf(qw, xj, a3);
        }
    }
    float qc0, qc1, qc2, qc3;
    softmax4(cvec, qc0, qc1, qc2, qc3);
    float xi = bf2f(h[(size_t)wid * C1_OUT + lane]);
    a0 = fmaf(qc0, xi, a0); a1 = fmaf(qc1, xi, a1);
    a2 = fmaf(qc2, xi, a2); a3 = fmaf(qc3, xi, a3);
    float inv = 1.f / (float)(e1 - e0 + 1);
    arow[(size_t)wid * 256 + 0 * C1_OUT + lane] = f2bf(a0 * inv);
    arow[(size_t)wid * 256 + 1 * C1_OUT + lane] = f2bf(a1 * inv);
    arow[(size_t)wid * 256 + 2 * C1_OUT + lane] = f2bf(a2 * inv);
    arow[(size_t)wid * 256 + 3 * C1_OUT + lane] = f2bf(a3 * inv);
}

// ---------------- merged weight prep (all 4 matrices, one launch) ----------
__global__ void k_prepAll(const float* __restrict__ W1, unsigned short* __restrict__ B1,
                          const float* __restrict__ W2, unsigned short* __restrict__ B2,
                          const float* __restrict__ Wf, unsigned short* __restrict__ Bf,
                          const float* __restrict__ Wc, unsigned short* __restrict__ Bc) {
    int idx = blockIdx.x * blockDim.x + threadIdx.x;
    if (idx < 8192) {                       // conv1: K=128 M=64 IN=32
        int o = idx / 128, j = idx % 128;
        int hh = j / 32, k = j % 32;
        B1[idx] = f2bf(W1[k * (HEADS * 64) + hh * 64 + o]);
    } else if (idx < 40960) {               // conv2: K=256 M=128 IN=64
        int i = idx - 8192;
        int o = i / 256, j = i % 256;
        int hh = j / 64, k = j % 64;
        B2[i] = f2bf(W2[k * (HEADS * 128) + hh * 128 + o]);
    } else if (idx < 73728) {               // fc1: K=128 M=256 transpose
        int i = idx - 40960;
        int o = i / 128, j = i % 128;
        Bf[i] = f2bf(Wf[j * 256 + o]);
    } else if (idx < 81920) {               // fc2: pad 25->32, K=256
        int i = idx - 73728;
        int o = i >> 8, k = i & 255;
        Bc[i] = f2bf(o < NCLS ? Wc[k * NCLS + o] : 0.f);
    }
}

// ---------------- MFMA GEMM: D = bf16(elu(A @ Bt^T + bias)), A bf16 --------
template<int K, int M>
__global__ __launch_bounds__(256) void k_mgemm(
    const unsigned short* __restrict__ A, const unsigned short* __restrict__ Bt,
    const float* __restrict__ bias, unsigned short* __restrict__ D, int n) {
    constexpr int CPW = M / 4;
    constexpr int NCF = CPW / 16;
    constexpr int NKC = K / 32;
    __shared__ unsigned short Al[64 * K];
    int tid = threadIdx.x;
    int w = tid >> 6, l = tid & 63;
    int l16 = l & 15, l4 = l >> 4;
    int rowbase = blockIdx.x * 64;

    bf16x8 bfr[NCF][NKC];
#pragma unroll
    for (int c = 0; c < NCF; ++c)
#pragma unroll
        for (int t = 0; t < NKC; ++t) {
            int col = w * CPW + c * 16 + l16;
            int k = t * 32 + l4 * 8;
            bfr[c][t] = *(const bf16x8*)(Bt + (size_t)col * K + k);
        }

    constexpr int CHUNKS = 64 * K / 8;
    for (int idx = tid; idx < CHUNKS; idx += 256) {
        int row = idx / (K / 8);
        int kb = (idx % (K / 8)) * 8;
        int grow = rowbase + row;
        uint4 u;
        if (grow < n) u = *(const uint4*)(A + (size_t)grow * K + kb);
        else          u.x = u.y = u.z = u.w = 0u;
        int byte = ((row * K + kb) * 2) ^ ((row & 7) << 4);
        *(uint4*)((char*)Al + byte) = u;
    }
    __syncthreads();

#pragma unroll
    for (int r = 0; r < 4; ++r) {
        bf16x8 af[NKC];
        int row = r * 16 + l16;
#pragma unroll
        for (int t = 0; t < NKC; ++t) {
            int byte = ((row * K + t * 32 + l4 * 8) * 2) ^ ((row & 7) << 4);
            af[t] = *(bf16x8*)((char*)Al + byte);
        }
#pragma unroll
        for (int c = 0; c < NCF; ++c) {
            f32x4 acc = {0.f, 0.f, 0.f, 0.f};
#pragma unroll
            for (int t = 0; t < NKC; ++t)
                acc = __builtin_amdgcn_mfma_f32_16x16x32_bf16(af[t], bfr[c][t], acc, 0, 0, 0);
            int col = w * CPW + c * 16 + l16;
            float bv = bias[col];
#pragma unroll
            for (int j = 0; j < 4; ++j) {
                int grow = rowbase + r * 16 + l4 * 4 + j;
                if (grow < n)
                    D[(size_t)grow * M + col] = f2bf(elu_f(acc[j] + bv));
            }
        }
    }
}

// ---------------- fused head: fc1 in LDS -> fc2 + log_softmax --------------
__global__ __launch_bounds__(256) void k_head(
    const unsigned short* __restrict__ A, const unsigned short* __restrict__ Btf,
    const float* __restrict__ bias1, const unsigned short* __restrict__ Btc,
    const float* __restrict__ bias2, float* __restrict__ out, int n) {
    __shared__ unsigned short Al[64 * 128];   // 16 KB
    __shared__ unsigned short Hl[64 * 256];   // 32 KB
    int tid = threadIdx.x;
    int w = tid >> 6, l = tid & 63;
    int l16 = l & 15, l4 = l >> 4;
    int rowbase = blockIdx.x * 64;

    bf16x8 bfr[4][4];
#pragma unroll
    for (int c = 0; c < 4; ++c)
#pragma unroll
        for (int t = 0; t < 4; ++t) {
            int col = w * 64 + c * 16 + l16;
            int k = t * 32 + l4 * 8;
            bfr[c][t] = *(const bf16x8*)(Btf + (size_t)col * 128 + k);
        }

    for (int idx = tid; idx < 1024; idx += 256) {
        int row = idx >> 4;
        int kb = (idx & 15) * 8;
        int grow = rowbase + row;
        uint4 u;
        if (grow < n) u = *(const uint4*)(A + (size_t)grow * 128 + kb);
        else          u.x = u.y = u.z = u.w = 0u;
        int byte = ((row * 128 + kb) * 2) ^ ((row & 7) << 4);
        *(uint4*)((char*)Al + byte) = u;
    }
    __syncthreads();

#pragma unroll
    for (int r = 0; r < 4; ++r) {
        bf16x8 af[4];
        int row = r * 16 + l16;
#pragma unroll
        for (int t = 0; t < 4; ++t) {
            int byte = ((row * 128 + t * 32 + l4 * 8) * 2) ^ ((row & 7) << 4);
            af[t] = *(bf16x8*)((char*)Al + byte);
        }
#pragma unroll
        for (int c = 0; c < 4; ++c) {
            f32x4 acc = {0.f, 0.f, 0.f, 0.f};
#pragma unroll
            for (int t = 0; t < 4; ++t)
                acc = __builtin_amdgcn_mfma_f32_16x16x32_bf16(af[t], bfr[c][t], acc, 0, 0, 0);
            int col = w * 64 + c * 16 + l16;
            float bv = bias1[col];
#pragma unroll
            for (int j = 0; j < 4; ++j) {
                int lrow = r * 16 + l4 * 4 + j;
                unsigned short v = f2bf(elu_f(acc[j] + bv));
                int byte = ((lrow * 256 + col) * 2) ^ ((lrow & 7) << 4);
                *(unsigned short*)((char*)Hl + byte) = v;
            }
        }
    }
    __syncthreads();

    bf16x8 b0[8], b1[8];
#pragma unroll
    for (int t = 0; t < 8; ++t) {
        int k = t * 32 + l4 * 8;
        b0[t] = *(const bf16x8*)(Btc + (size_t)l16 * LIN + k);
        b1[t] = *(const bf16x8*)(Btc + (size_t)(16 + l16) * LIN + k);
    }
    float bb0 = bias2[l16];
    bool hi_ok = (l16 < NCLS - 16);
    float bb1 = hi_ok ? bias2[16 + l16] : 0.f;

    int lrow = w * 16 + l16;
    bf16x8 af[8];
#pragma unroll
    for (int t = 0; t < 8; ++t) {
        int byte = ((lrow * 256 + t * 32 + l4 * 8) * 2) ^ ((lrow & 7) << 4);
        af[t] = *(bf16x8*)((char*)Hl + byte);
    }
    f32x4 acc0 = {0.f, 0.f, 0.f, 0.f}, acc1 = {0.f, 0.f, 0.f, 0.f};
#pragma unroll
    for (int t = 0; t < 8; ++t) {
        acc0 = __builtin_amdgcn_mfma_f32_16x16x32_bf16(af[t], b0[t], acc0, 0, 0, 0);
        acc1 = __builtin_amdgcn_mfma_f32_16x16x32_bf16(af[t], b1[t], acc1, 0, 0, 0);
    }
#pragma unroll
    for (int j = 0; j < 4; ++j) {
        float v0 = acc0[j] + bb0;
        float v1 = acc1[j] + bb1;
        float m = fmaxf(v0, hi_ok ? v1 : -1e30f);
#pragma unroll
        for (int msk = 8; msk >= 1; msk >>= 1)
            m = fmaxf(m, __shfl_xor(m, msk, 16));
        float s = __expf(v0 - m) + (hi_ok ? __expf(v1 - m) : 0.f);
#pragma unroll
        for (int msk = 8; msk >= 1; msk >>= 1)
            s += __shfl_xor(s, msk, 16);
        float lse = m + __logf(s);
        int ro = rowbase + w * 16 + l4 * 4 + j;
        if (ro < n) {
            out[(size_t)ro * NCLS + l16] = v0 - lse;
            if (hi_ok) out[(size_t)ro * NCLS + 16 + l16] = v1 - lse;
        }
    }
}

extern "C" void kernel_launch(void* const* d_in, const int* in_sizes, int n_in,
                              void* d_out, int out_size, void* d_ws, size_t ws_size,
                              hipStream_t stream) {
    const float* x     = (const float*)d_in[0];
    const int*   eidx  = (const int*)d_in[1];
    const float* fc0_w = (const float*)d_in[2];
    const float* fc0_b = (const float*)d_in[3];
    const float* c1w   = (const float*)d_in[4];
    const float* c1u   = (const float*)d_in[5];
    const float* c1c   = (const float*)d_in[6];
    const float* c1b   = (const float*)d_in[7];
    const float* c2w   = (const float*)d_in[8];
    const float* c2u   = (const float*)d_in[9];
    const float* c2c   = (const float*)d_in[10];
    const float* c2b   = (const float*)d_in[11];
    const float* fc1w  = (const float*)d_in[12];
    const float* fc1b  = (const float*)d_in[13];
    const float* fc2w  = (const float*)d_in[14];
    const float* fc2b  = (const float*)d_in[15];

    int n_nodes = in_sizes[0] / F_IN;   // 50000
    int ne      = in_sizes[1] / 2;      // 800000

    // ---- workspace layout (float units), liveness-aliased ----
    auto align4 = [](size_t v) { return (v + 3) & ~(size_t)3; };
    float* ws = (float*)d_ws;
    size_t t = 0;
    size_t off_o = t; t += align4((size_t)n_nodes + 1);
    size_t cur_o = t; t += align4((size_t)n_nodes);
    size_t blk_o = t; t += 64;
    size_t p_o   = t; t += align4((size_t)n_nodes * 4);
    size_t h1_o  = t; t += align4((size_t)n_nodes * 32);   // n*64 bf16
    size_t A_o   = t; t += align4((size_t)n_nodes * 128);  // arow1|arow2 (n*256 bf16)
    // B region: {h0, ssrc} early | h2 late
    size_t B_o   = t;
    size_t h0_o  = B_o;                                    // n*32 bf16 = 16n fl
    size_t ss_o  = align4(h0_o + (size_t)n_nodes * 16);    // ssrc: int = ne fl
    size_t B_end = ss_o + (size_t)ne;
    size_t B_sz  = B_end - B_o;
    size_t h2_sz = (size_t)n_nodes * 64;                   // n*128 bf16
    t = B_o + (B_sz > h2_sz ? B_sz : h2_sz);
    size_t bt1_o = t; t += 4096;
    size_t bt2_o = t; t += 16384;
    size_t btf_o = t; t += 16384;
    size_t btc_o = t; t += 4096;

    int*    offa   = (int*)(ws + off_o);
    int*    cur    = (int*)(ws + cur_o);
    int*    blksum = (int*)(ws + blk_o);
    float*  p      = ws + p_o;
    unsigned short* h1    = (unsigned short*)(ws + h1_o);
    unsigned short* arow1 = (unsigned short*)(ws + A_o);
    unsigned short* arow2 = (unsigned short*)(ws + A_o);
    unsigned short* h0    = (unsigned short*)(ws + h0_o);
    int*    ssrc   = (int*)(ws + ss_o);
    unsigned short* h2    = (unsigned short*)(ws + B_o);   // after ssrc dead
    unsigned short* bt1 = (unsigned short*)(ws + bt1_o);
    unsigned short* bt2 = (unsigned short*)(ws + bt2_o);
    unsigned short* btf = (unsigned short*)(ws + btf_o);
    unsigned short* btc = (unsigned short*)(ws + btc_o);
    float*  out    = (float*)d_out;

    int nblk = (n_nodes + SCAN_BS - 1) / SCAN_BS;
    int npb  = (n_nodes + NBIN - 1) / NBIN;   // nodes per XCD bin

    k_prepAll<<<(81920 + 255) / 256, 256, 0, stream>>>(c1w, bt1, c2w, bt2, fc1w, btf, fc2w, btc);
    hipMemsetAsync(cur, 0, (size_t)n_nodes * sizeof(int), stream);

    k_fc0<<<(n_nodes * 32 + 255) / 256, 256, 0, stream>>>(x, fc0_w, fc0_b, c1u, h0, p, n_nodes);
    k_deg<<<NBIN * 512, 256, 0, stream>>>(eidx + ne, cur, ne, npb);
    k_scan_a<<<nblk, SCAN_BS, 0, stream>>>(cur, offa, blksum, n_nodes);
    k_scan_b<<<1, 64, 0, stream>>>(blksum, offa, nblk, n_nodes);
    k_scan_c<<<(n_nodes + 255) / 256, 256, 0, stream>>>(offa, cur, blksum, n_nodes);
    k_scatter<<<NBIN * 512, 256, 0, stream>>>(eidx, cur, ssrc, ne, npb);

    int ngrid = (n_nodes + 63) / 64;

    // conv1 (p1 computed in k_fc0)
    k_agg1<<<(n_nodes * 64 + 255) / 256, 256, 0, stream>>>(h0, offa, ssrc, p, c1c, arow1, n_nodes);
    k_mgemm<128, 64><<<ngrid, 256, 0, stream>>>(arow1, bt1, c1b, h1, n_nodes);

    // conv2
    k_proj<C1_OUT><<<(n_nodes + 255) / 256, 256, 0, stream>>>(h1, c2u, p, n_nodes);
    k_agg2<<<(n_nodes * 64 + 255) / 256, 256, 0, stream>>>(h1, offa, ssrc, p, c2c, arow2, n_nodes);
    k_mgemm<256, 128><<<ngrid, 256, 0, stream>>>(arow2, bt2, c2b, h2, n_nodes);

    // fused head: fc1 + fc2 + log_softmax
    k_head<<<ngrid, 256, 0, stream>>>(h2, btf, fc1b, btc, fc2b, out, n_nodes);
}